// Round 1
// baseline (565.133 us; speedup 1.0000x reference)
//
#include <hip/hip_runtime.h>

// GraphSAGE 3-layer, fp32, CSR-per-call (no fp atomics in aggregation).
// Layout of d_ws (ints unless noted):
//   deg[N] | cursor[N] | offs[N+4] | partial[128] | scol[E] | agg fN*64 | h1 fN*64 | h2 fN*64

#define CH 64

__global__ __launch_bounds__(256) void k_count(const int* __restrict__ row,
                                               int* __restrict__ deg, int E) {
    int e = blockIdx.x * 256 + threadIdx.x;
    if (e < E) atomicAdd(&deg[row[e]], 1);
}

__global__ __launch_bounds__(256) void k_scan1(const int* __restrict__ deg,
                                               int* __restrict__ partial, int N) {
    __shared__ int ts[256];
    int t = threadIdx.x;
    int g0 = blockIdx.x * 1024 + t * 4;
    int s = 0;
#pragma unroll
    for (int i = 0; i < 4; ++i)
        if (g0 + i < N) s += deg[g0 + i];
    ts[t] = s;
    __syncthreads();
    for (int off = 128; off >= 1; off >>= 1) {
        if (t < off) ts[t] += ts[t + off];
        __syncthreads();
    }
    if (t == 0) partial[blockIdx.x] = ts[0];
}

__global__ void k_scan2(int* partial, int nb) {
    if (threadIdx.x == 0) {
        int run = 0;
        for (int b = 0; b < nb; ++b) { int v = partial[b]; partial[b] = run; run += v; }
    }
}

__global__ __launch_bounds__(256) void k_scan3(const int* __restrict__ deg,
                                               const int* __restrict__ partial,
                                               int* __restrict__ offs, int N) {
    __shared__ int ts[256];
    int t = threadIdx.x;
    int g0 = blockIdx.x * 1024 + t * 4;
    int d[4];
    int s = 0;
#pragma unroll
    for (int i = 0; i < 4; ++i) {
        d[i] = (g0 + i < N) ? deg[g0 + i] : 0;
        s += d[i];
    }
    ts[t] = s;
    __syncthreads();
    // Hillis-Steele inclusive scan over thread sums
    for (int off = 1; off < 256; off <<= 1) {
        int v = (t >= off) ? ts[t - off] : 0;
        __syncthreads();
        ts[t] += v;
        __syncthreads();
    }
    int run = partial[blockIdx.x] + ts[t] - s;  // exclusive prefix for this thread
#pragma unroll
    for (int i = 0; i < 4; ++i) {
        if (g0 + i <= N) offs[g0 + i] = run;
        run += d[i];
    }
}

__global__ __launch_bounds__(256) void k_scatter(const int* __restrict__ row,
                                                 const int* __restrict__ col,
                                                 const int* __restrict__ offs,
                                                 int* __restrict__ cursor,
                                                 int* __restrict__ scol, int E) {
    int e = blockIdx.x * 256 + threadIdx.x;
    if (e < E) {
        int r = row[e];
        int p = atomicAdd(&cursor[r], 1);
        scol[offs[r] + p] = col[e];
    }
}

// Mean-aggregate: one wave (64 lanes) per node, lane = channel.
__global__ __launch_bounds__(256) void k_agg(const float* __restrict__ X,
                                             const int* __restrict__ offs,
                                             const int* __restrict__ scol,
                                             float* __restrict__ AGG, int N) {
    int node = blockIdx.x * 4 + (threadIdx.x >> 6);
    int lane = threadIdx.x & 63;
    if (node >= N) return;
    int s = offs[node], e = offs[node + 1];
    float a0 = 0.f, a1 = 0.f, a2 = 0.f, a3 = 0.f;
    int j = s;
    for (; j + 4 <= e; j += 4) {
        int c0 = scol[j], c1 = scol[j + 1], c2 = scol[j + 2], c3 = scol[j + 3];
        a0 += X[c0 * CH + lane];
        a1 += X[c1 * CH + lane];
        a2 += X[c2 * CH + lane];
        a3 += X[c3 * CH + lane];
    }
    for (; j < e; ++j) a0 += X[scol[j] * CH + lane];
    float acc = (a0 + a1) + (a2 + a3);
    float inv = (e > s) ? 1.0f / (float)(e - s) : 1.0f;
    AGG[node * CH + lane] = acc * inv;
}

// h[n][o] = relu( sum_k cat(x,agg)[n][k] * W[o][k] + b[o] ), W is [64][128] row-major.
__global__ __launch_bounds__(256) void k_gemm(const float* __restrict__ A,
                                              const float* __restrict__ AGG,
                                              const float* __restrict__ W,
                                              const float* __restrict__ bias,
                                              float* __restrict__ OUT, int N, int do_relu) {
    __shared__ float As[128][68];  // [k][n], stride 68 floats: 16B-aligned rows, bank-rotated
    __shared__ float Ws[128][68];  // [k][o]
    int t = threadIdx.x;
    int base = blockIdx.x * 64;

    // stage W (64x128 -> Ws[k][o])
    {
        int o = t >> 2;
        int k0 = (t & 3) * 32;
        const float4* wr = (const float4*)(W + o * 128 + k0);
#pragma unroll
        for (int q = 0; q < 8; ++q) {
            float4 v = wr[q];
            Ws[k0 + q * 4 + 0][o] = v.x;
            Ws[k0 + q * 4 + 1][o] = v.y;
            Ws[k0 + q * 4 + 2][o] = v.z;
            Ws[k0 + q * 4 + 3][o] = v.w;
        }
    }
    // stage A-tile: As[k][n] = x[base+n][k] (k<64), agg[base+n][k-64] (k>=64)
    {
        int n = t >> 2;
        int c0 = (t & 3) * 16;
        int gn = base + n;
        if (gn < N) {
            const float4* xr = (const float4*)(A + gn * CH + c0);
            const float4* gr = (const float4*)(AGG + gn * CH + c0);
#pragma unroll
            for (int q = 0; q < 4; ++q) {
                float4 v = xr[q];
                As[c0 + q * 4 + 0][n] = v.x;
                As[c0 + q * 4 + 1][n] = v.y;
                As[c0 + q * 4 + 2][n] = v.z;
                As[c0 + q * 4 + 3][n] = v.w;
                float4 g = gr[q];
                As[64 + c0 + q * 4 + 0][n] = g.x;
                As[64 + c0 + q * 4 + 1][n] = g.y;
                As[64 + c0 + q * 4 + 2][n] = g.z;
                As[64 + c0 + q * 4 + 3][n] = g.w;
            }
        } else {
#pragma unroll
            for (int i = 0; i < 16; ++i) {
                As[c0 + i][n] = 0.f;
                As[64 + c0 + i][n] = 0.f;
            }
        }
    }
    __syncthreads();

    int o0 = (t & 15) * 4;
    int n0 = (t >> 4) * 4;
    float acc[4][4];
#pragma unroll
    for (int i = 0; i < 4; ++i)
#pragma unroll
        for (int jj = 0; jj < 4; ++jj) acc[i][jj] = 0.f;

#pragma unroll 4
    for (int k = 0; k < 128; ++k) {
        float4 a = *(const float4*)&As[k][n0];
        float4 w = *(const float4*)&Ws[k][o0];
        acc[0][0] += a.x * w.x; acc[0][1] += a.x * w.y; acc[0][2] += a.x * w.z; acc[0][3] += a.x * w.w;
        acc[1][0] += a.y * w.x; acc[1][1] += a.y * w.y; acc[1][2] += a.y * w.z; acc[1][3] += a.y * w.w;
        acc[2][0] += a.z * w.x; acc[2][1] += a.z * w.y; acc[2][2] += a.z * w.z; acc[2][3] += a.z * w.w;
        acc[3][0] += a.w * w.x; acc[3][1] += a.w * w.y; acc[3][2] += a.w * w.z; acc[3][3] += a.w * w.w;
    }

    float4 bv = *(const float4*)&bias[o0];
#pragma unroll
    for (int i = 0; i < 4; ++i) {
        int gn = base + n0 + i;
        if (gn < N) {
            float4 r;
            r.x = acc[i][0] + bv.x;
            r.y = acc[i][1] + bv.y;
            r.z = acc[i][2] + bv.z;
            r.w = acc[i][3] + bv.w;
            if (do_relu) {
                r.x = fmaxf(r.x, 0.f);
                r.y = fmaxf(r.y, 0.f);
                r.z = fmaxf(r.z, 0.f);
                r.w = fmaxf(r.w, 0.f);
            }
            *(float4*)(OUT + gn * CH + o0) = r;
        }
    }
}

// Layer 3 fused: out[n] = sum_c h2[n][c]*W3[c] + (1/deg)*sum_j sum_c h2[col_j][c]*W3[64+c] + b3
__global__ __launch_bounds__(256) void k_final(const float* __restrict__ H,
                                               const int* __restrict__ offs,
                                               const int* __restrict__ scol,
                                               const float* __restrict__ W3,
                                               const float* __restrict__ b3,
                                               float* __restrict__ out, int N) {
    int node = blockIdx.x * 4 + (threadIdx.x >> 6);
    int lane = threadIdx.x & 63;
    if (node >= N) return;
    int s = offs[node], e = offs[node + 1];
    float a0 = 0.f, a1 = 0.f, a2 = 0.f, a3 = 0.f;
    int j = s;
    for (; j + 4 <= e; j += 4) {
        int c0 = scol[j], c1 = scol[j + 1], c2 = scol[j + 2], c3 = scol[j + 3];
        a0 += H[c0 * CH + lane];
        a1 += H[c1 * CH + lane];
        a2 += H[c2 * CH + lane];
        a3 += H[c3 * CH + lane];
    }
    for (; j < e; ++j) a0 += H[scol[j] * CH + lane];
    float acc = (a0 + a1) + (a2 + a3);
    float inv = (e > s) ? 1.0f / (float)(e - s) : 1.0f;
    float v = H[node * CH + lane] * W3[lane] + acc * inv * W3[64 + lane];
#pragma unroll
    for (int off = 32; off >= 1; off >>= 1) v += __shfl_down(v, off, 64);
    if (lane == 0) out[node] = v + b3[0];
}

extern "C" void kernel_launch(void* const* d_in, const int* in_sizes, int n_in,
                              void* d_out, int out_size, void* d_ws, size_t ws_size,
                              hipStream_t stream) {
    const float* x   = (const float*)d_in[0];
    const int* eidx  = (const int*)d_in[1];
    const float* W1  = (const float*)d_in[2];
    const float* b1  = (const float*)d_in[3];
    const float* W2  = (const float*)d_in[4];
    const float* b2  = (const float*)d_in[5];
    const float* W3  = (const float*)d_in[6];
    const float* b3  = (const float*)d_in[7];
    float* out = (float*)d_out;

    const int N = in_sizes[0] / CH;
    const int E = in_sizes[1] / 2;
    const int* row = eidx;
    const int* col = eidx + E;

    int* deg     = (int*)d_ws;
    int* cursor  = deg + N;
    int* offs    = cursor + N;
    int* partial = offs + (N + 4);
    int* scol    = partial + 128;
    float* agg   = (float*)(scol + E);
    float* h1    = agg + (size_t)N * CH;
    float* h2    = h1 + (size_t)N * CH;

    // zero deg + cursor (contiguous)
    hipMemsetAsync(deg, 0, (size_t)2 * N * sizeof(int), stream);

    int ebl = (E + 255) / 256;
    int nb  = (N + 1 + 1023) / 1024;  // scan blocks (covers index N)
    int abl = (N + 3) / 4;            // 4 nodes per 256-thread block
    int gbl = (N + 63) / 64;

    k_count<<<ebl, 256, 0, stream>>>(row, deg, E);
    k_scan1<<<nb, 256, 0, stream>>>(deg, partial, N);
    k_scan2<<<1, 64, 0, stream>>>(partial, nb);
    k_scan3<<<nb, 256, 0, stream>>>(deg, partial, offs, N);
    k_scatter<<<ebl, 256, 0, stream>>>(row, col, offs, cursor, scol, E);

    // layer 1
    k_agg<<<abl, 256, 0, stream>>>(x, offs, scol, agg, N);
    k_gemm<<<gbl, 256, 0, stream>>>(x, agg, W1, b1, h1, N, 1);
    // layer 2
    k_agg<<<abl, 256, 0, stream>>>(h1, offs, scol, agg, N);
    k_gemm<<<gbl, 256, 0, stream>>>(h1, agg, W2, b2, h2, N, 1);
    // layer 3 (fused aggregate + [1,128] linear)
    k_final<<<abl, 256, 0, stream>>>(h2, offs, scol, W3, b3, out, N);
}

// Round 2
// 434.005 us; speedup vs baseline: 1.3021x; 1.3021x over previous
//
#include <hip/hip_runtime.h>

// GraphSAGE 3-layer, fp32. CSR built per-call via two-level counting sort
// (no random-line scatter: all global writes are block-owned contiguous spans).
//
// ws layout: offs[N+1] | scol[E] | agg fN*64 | h1 fN*64 | h2 fN*64
//            (ebuf[E] + hist + histsc + part alias the h2 region — h2 is
//             written only in layer-2 GEMM, long after the sort finishes)

#define CH 64
#define BKT_SHIFT 9
#define BKT_ROWS 512
#define NBLK 256  // pass A/B blocks; requires nbk <= 256 (N <= 131072)

// ---- Pass A: per-block bucket histogram, layout hist[bucket][NBLK] ----
__global__ __launch_bounds__(256) void k_hist(const int* __restrict__ row,
                                              int* __restrict__ hist,
                                              int E, int nbk, int per_blk) {
    __shared__ int h[256];
    int t = threadIdx.x;
    h[t] = 0;
    __syncthreads();
    int s = blockIdx.x * per_blk;
    int e = min(s + per_blk, E);
    for (int i = s + t; i < e; i += 256)
        atomicAdd(&h[row[i] >> BKT_SHIFT], 1);
    __syncthreads();
    if (t < nbk) hist[t * NBLK + blockIdx.x] = h[t];
}

// ---- generic 3-kernel exclusive scan over M ints ----
__global__ __launch_bounds__(256) void k_ssum(const int* __restrict__ a,
                                              int* __restrict__ part, int M) {
    __shared__ int ts[256];
    int t = threadIdx.x;
    int g0 = blockIdx.x * 1024 + t * 4;
    int s = 0;
#pragma unroll
    for (int i = 0; i < 4; ++i)
        if (g0 + i < M) s += a[g0 + i];
    ts[t] = s;
    __syncthreads();
    for (int off = 128; off >= 1; off >>= 1) {
        if (t < off) ts[t] += ts[t + off];
        __syncthreads();
    }
    if (t == 0) part[blockIdx.x] = ts[0];
}

__global__ void k_sser(int* part, int nb) {
    if (threadIdx.x == 0) {
        int run = 0;
        for (int b = 0; b < nb; ++b) { int v = part[b]; part[b] = run; run += v; }
    }
}

__global__ __launch_bounds__(256) void k_sscan(const int* __restrict__ a,
                                               const int* __restrict__ part,
                                               int* __restrict__ o, int M) {
    __shared__ int ts[256];
    int t = threadIdx.x;
    int g0 = blockIdx.x * 1024 + t * 4;
    int d[4];
    int s = 0;
#pragma unroll
    for (int i = 0; i < 4; ++i) {
        d[i] = (g0 + i < M) ? a[g0 + i] : 0;
        s += d[i];
    }
    ts[t] = s;
    __syncthreads();
    for (int off = 1; off < 256; off <<= 1) {
        int v = (t >= off) ? ts[t - off] : 0;
        __syncthreads();
        ts[t] += v;
        __syncthreads();
    }
    int run = part[blockIdx.x] + ts[t] - s;
#pragma unroll
    for (int i = 0; i < 4; ++i) {
        if (g0 + i < M) o[g0 + i] = run;
        run += d[i];
    }
}

// ---- Pass B: place packed (rowlocal<<17 | col) into bucket-ordered ebuf ----
__global__ __launch_bounds__(256) void k_binscatter(const int* __restrict__ row,
                                                    const int* __restrict__ col,
                                                    const int* __restrict__ histsc,
                                                    int* __restrict__ ebuf,
                                                    int E, int nbk, int per_blk) {
    __shared__ int cur[256];
    int t = threadIdx.x;
    cur[t] = (t < nbk) ? histsc[t * NBLK + blockIdx.x] : 0;
    __syncthreads();
    int s = blockIdx.x * per_blk;
    int e = min(s + per_blk, E);
    for (int i = s + t; i < e; i += 256) {
        int r = row[i];
        int b = r >> BKT_SHIFT;
        int p = atomicAdd(&cur[b], 1);
        ebuf[p] = ((r & (BKT_ROWS - 1)) << 17) | col[i];
    }
}

// ---- Pass C: per-bucket CSR build; all global writes contiguous per block ----
__global__ __launch_bounds__(256) void k_build(const int* __restrict__ histsc,
                                               const int* __restrict__ ebuf,
                                               int* __restrict__ offs,
                                               int* __restrict__ scol,
                                               int N, int E, int nbk) {
    __shared__ int cnt[BKT_ROWS];
    __shared__ int loff[BKT_ROWS];
    __shared__ int ts[256];
    int b = blockIdx.x, t = threadIdx.x;
    int g0 = histsc[b * NBLK];
    int g1 = (b + 1 < nbk) ? histsc[(b + 1) * NBLK] : E;
    cnt[t] = 0;
    cnt[t + 256] = 0;
    __syncthreads();
    for (int i = g0 + t; i < g1; i += 256)
        atomicAdd(&cnt[((unsigned)ebuf[i]) >> 17], 1);
    __syncthreads();
    int c0 = cnt[2 * t], c1 = cnt[2 * t + 1];
    ts[t] = c0 + c1;
    __syncthreads();
    for (int off = 1; off < 256; off <<= 1) {
        int v = (t >= off) ? ts[t - off] : 0;
        __syncthreads();
        ts[t] += v;
        __syncthreads();
    }
    int ex = ts[t] - (c0 + c1);
    loff[2 * t] = ex;
    loff[2 * t + 1] = ex + c0;
    __syncthreads();
    int r0 = b << BKT_SHIFT;
#pragma unroll
    for (int r = t; r < BKT_ROWS; r += 256)
        if (r0 + r < N) offs[r0 + r] = g0 + loff[r];
    if (b == nbk - 1 && t == 0) offs[N] = E;
    // reuse cnt as placement cursors
    cnt[t] = 0;
    cnt[t + 256] = 0;
    __syncthreads();
    for (int i = g0 + t; i < g1; i += 256) {
        unsigned v = (unsigned)ebuf[i];
        int rl = v >> 17;
        int c = (int)(v & 0x1FFFFu);
        int p = atomicAdd(&cnt[rl], 1);
        scol[g0 + loff[rl] + p] = c;
    }
}

// ---- Mean-aggregate: one wave per node, lane = channel ----
__global__ __launch_bounds__(256) void k_agg(const float* __restrict__ X,
                                             const int* __restrict__ offs,
                                             const int* __restrict__ scol,
                                             float* __restrict__ AGG, int N) {
    int node = blockIdx.x * 4 + (threadIdx.x >> 6);
    int lane = threadIdx.x & 63;
    if (node >= N) return;
    int s = offs[node], e = offs[node + 1];
    float a0 = 0.f, a1 = 0.f, a2 = 0.f, a3 = 0.f;
    int j = s;
    for (; j + 4 <= e; j += 4) {
        int c0 = scol[j], c1 = scol[j + 1], c2 = scol[j + 2], c3 = scol[j + 3];
        a0 += X[c0 * CH + lane];
        a1 += X[c1 * CH + lane];
        a2 += X[c2 * CH + lane];
        a3 += X[c3 * CH + lane];
    }
    for (; j < e; ++j) a0 += X[scol[j] * CH + lane];
    float acc = (a0 + a1) + (a2 + a3);
    float inv = (e > s) ? 1.0f / (float)(e - s) : 1.0f;
    AGG[node * CH + lane] = acc * inv;
}

// ---- h[n][o] = relu(cat(x,agg)[n] . W[o] + b[o]), W [64][128] row-major ----
__global__ __launch_bounds__(256) void k_gemm(const float* __restrict__ A,
                                              const float* __restrict__ AGG,
                                              const float* __restrict__ W,
                                              const float* __restrict__ bias,
                                              float* __restrict__ OUT, int N, int do_relu) {
    __shared__ float As[128][68];
    __shared__ float Ws[128][68];
    int t = threadIdx.x;
    int base = blockIdx.x * 64;

    {
        int o = t >> 2;
        int k0 = (t & 3) * 32;
        const float4* wr = (const float4*)(W + o * 128 + k0);
#pragma unroll
        for (int q = 0; q < 8; ++q) {
            float4 v = wr[q];
            Ws[k0 + q * 4 + 0][o] = v.x;
            Ws[k0 + q * 4 + 1][o] = v.y;
            Ws[k0 + q * 4 + 2][o] = v.z;
            Ws[k0 + q * 4 + 3][o] = v.w;
        }
    }
    {
        int n = t >> 2;
        int c0 = (t & 3) * 16;
        int gn = base + n;
        if (gn < N) {
            const float4* xr = (const float4*)(A + gn * CH + c0);
            const float4* gr = (const float4*)(AGG + gn * CH + c0);
#pragma unroll
            for (int q = 0; q < 4; ++q) {
                float4 v = xr[q];
                As[c0 + q * 4 + 0][n] = v.x;
                As[c0 + q * 4 + 1][n] = v.y;
                As[c0 + q * 4 + 2][n] = v.z;
                As[c0 + q * 4 + 3][n] = v.w;
                float4 g = gr[q];
                As[64 + c0 + q * 4 + 0][n] = g.x;
                As[64 + c0 + q * 4 + 1][n] = g.y;
                As[64 + c0 + q * 4 + 2][n] = g.z;
                As[64 + c0 + q * 4 + 3][n] = g.w;
            }
        } else {
#pragma unroll
            for (int i = 0; i < 16; ++i) {
                As[c0 + i][n] = 0.f;
                As[64 + c0 + i][n] = 0.f;
            }
        }
    }
    __syncthreads();

    int o0 = (t & 15) * 4;
    int n0 = (t >> 4) * 4;
    float acc[4][4];
#pragma unroll
    for (int i = 0; i < 4; ++i)
#pragma unroll
        for (int jj = 0; jj < 4; ++jj) acc[i][jj] = 0.f;

#pragma unroll 4
    for (int k = 0; k < 128; ++k) {
        float4 a = *(const float4*)&As[k][n0];
        float4 w = *(const float4*)&Ws[k][o0];
        acc[0][0] += a.x * w.x; acc[0][1] += a.x * w.y; acc[0][2] += a.x * w.z; acc[0][3] += a.x * w.w;
        acc[1][0] += a.y * w.x; acc[1][1] += a.y * w.y; acc[1][2] += a.y * w.z; acc[1][3] += a.y * w.w;
        acc[2][0] += a.z * w.x; acc[2][1] += a.z * w.y; acc[2][2] += a.z * w.z; acc[2][3] += a.z * w.w;
        acc[3][0] += a.w * w.x; acc[3][1] += a.w * w.y; acc[3][2] += a.w * w.z; acc[3][3] += a.w * w.w;
    }

    float4 bv = *(const float4*)&bias[o0];
#pragma unroll
    for (int i = 0; i < 4; ++i) {
        int gn = base + n0 + i;
        if (gn < N) {
            float4 r;
            r.x = acc[i][0] + bv.x;
            r.y = acc[i][1] + bv.y;
            r.z = acc[i][2] + bv.z;
            r.w = acc[i][3] + bv.w;
            if (do_relu) {
                r.x = fmaxf(r.x, 0.f);
                r.y = fmaxf(r.y, 0.f);
                r.z = fmaxf(r.z, 0.f);
                r.w = fmaxf(r.w, 0.f);
            }
            *(float4*)(OUT + gn * CH + o0) = r;
        }
    }
}

// ---- Layer 3 fused: aggregate + [1,128] linear ----
__global__ __launch_bounds__(256) void k_final(const float* __restrict__ H,
                                               const int* __restrict__ offs,
                                               const int* __restrict__ scol,
                                               const float* __restrict__ W3,
                                               const float* __restrict__ b3,
                                               float* __restrict__ out, int N) {
    int node = blockIdx.x * 4 + (threadIdx.x >> 6);
    int lane = threadIdx.x & 63;
    if (node >= N) return;
    int s = offs[node], e = offs[node + 1];
    float a0 = 0.f, a1 = 0.f, a2 = 0.f, a3 = 0.f;
    int j = s;
    for (; j + 4 <= e; j += 4) {
        int c0 = scol[j], c1 = scol[j + 1], c2 = scol[j + 2], c3 = scol[j + 3];
        a0 += H[c0 * CH + lane];
        a1 += H[c1 * CH + lane];
        a2 += H[c2 * CH + lane];
        a3 += H[c3 * CH + lane];
    }
    for (; j < e; ++j) a0 += H[scol[j] * CH + lane];
    float acc = (a0 + a1) + (a2 + a3);
    float inv = (e > s) ? 1.0f / (float)(e - s) : 1.0f;
    float v = H[node * CH + lane] * W3[lane] + acc * inv * W3[64 + lane];
#pragma unroll
    for (int off = 32; off >= 1; off >>= 1) v += __shfl_down(v, off, 64);
    if (lane == 0) out[node] = v + b3[0];
}

extern "C" void kernel_launch(void* const* d_in, const int* in_sizes, int n_in,
                              void* d_out, int out_size, void* d_ws, size_t ws_size,
                              hipStream_t stream) {
    const float* x   = (const float*)d_in[0];
    const int* eidx  = (const int*)d_in[1];
    const float* W1  = (const float*)d_in[2];
    const float* b1  = (const float*)d_in[3];
    const float* W2  = (const float*)d_in[4];
    const float* b2  = (const float*)d_in[5];
    const float* W3  = (const float*)d_in[6];
    const float* b3  = (const float*)d_in[7];
    float* out = (float*)d_out;

    const int N = in_sizes[0] / CH;
    const int E = in_sizes[1] / 2;
    const int* row = eidx;
    const int* col = eidx + E;

    int* offs  = (int*)d_ws;                 // N+1
    int* scol  = offs + (N + 1);             // E
    float* agg = (float*)(scol + E);
    float* h1  = agg + (size_t)N * CH;
    float* h2  = h1 + (size_t)N * CH;
    // sort scratch aliases h2's region (h2 written only after sort completes)
    int* ebuf   = (int*)h2;                  // E
    int nbk     = (N + BKT_ROWS - 1) >> BKT_SHIFT;
    int* hist   = ebuf + E;                  // nbk*NBLK
    int* histsc = hist + (size_t)nbk * NBLK; // nbk*NBLK
    int* part   = histsc + (size_t)nbk * NBLK;  // 64

    int M = nbk * NBLK;
    int per_blk = (E + NBLK - 1) / NBLK;
    int mb = (M + 1023) / 1024;
    int abl = (N + 3) / 4;
    int gbl = (N + 63) / 64;

    // CSR build via two-level counting sort
    k_hist<<<NBLK, 256, 0, stream>>>(row, hist, E, nbk, per_blk);
    k_ssum<<<mb, 256, 0, stream>>>(hist, part, M);
    k_sser<<<1, 64, 0, stream>>>(part, mb);
    k_sscan<<<mb, 256, 0, stream>>>(hist, part, histsc, M);
    k_binscatter<<<NBLK, 256, 0, stream>>>(row, col, histsc, ebuf, E, nbk, per_blk);
    k_build<<<nbk, 256, 0, stream>>>(histsc, ebuf, offs, scol, N, E, nbk);

    // layer 1
    k_agg<<<abl, 256, 0, stream>>>(x, offs, scol, agg, N);
    k_gemm<<<gbl, 256, 0, stream>>>(x, agg, W1, b1, h1, N, 1);
    // layer 2
    k_agg<<<abl, 256, 0, stream>>>(h1, offs, scol, agg, N);
    k_gemm<<<gbl, 256, 0, stream>>>(h1, agg, W2, b2, h2, N, 1);
    // layer 3
    k_final<<<abl, 256, 0, stream>>>(h2, offs, scol, W3, b3, out, N);
}

// Round 3
// 396.801 us; speedup vs baseline: 1.4242x; 1.0938x over previous
//
#include <hip/hip_runtime.h>
#include <hip/hip_fp16.h>

// GraphSAGE 3-layer. CSR via two-level counting sort (R1). Feature tables
// stored fp16 to halve gather traffic; all math fp32.
//
// ws: offs[N+1] | scol[E] | xh h[N*64] | h1 h[N*64] | h2 h[N*64] | agg f[N*64]
//     (sort scratch ebuf/hist/histsc/part aliases the agg region — agg is
//      first written by k_agg, after the sort completes)

#define CH 64
#define BKT_SHIFT 9
#define BKT_ROWS 512
#define NBLK 256  // pass A/B blocks; requires nbk <= 256 (N <= 131072)

// ---- Pass A: per-block bucket histogram, layout hist[bucket][NBLK] ----
__global__ __launch_bounds__(256) void k_hist(const int* __restrict__ row,
                                              int* __restrict__ hist,
                                              int E, int nbk, int per_blk) {
    __shared__ int h[256];
    int t = threadIdx.x;
    h[t] = 0;
    __syncthreads();
    int s = blockIdx.x * per_blk;
    int e = min(s + per_blk, E);
    for (int i = s + t; i < e; i += 256)
        atomicAdd(&h[row[i] >> BKT_SHIFT], 1);
    __syncthreads();
    if (t < nbk) hist[t * NBLK + blockIdx.x] = h[t];
}

// ---- generic 3-kernel exclusive scan over M ints ----
__global__ __launch_bounds__(256) void k_ssum(const int* __restrict__ a,
                                              int* __restrict__ part, int M) {
    __shared__ int ts[256];
    int t = threadIdx.x;
    int g0 = blockIdx.x * 1024 + t * 4;
    int s = 0;
#pragma unroll
    for (int i = 0; i < 4; ++i)
        if (g0 + i < M) s += a[g0 + i];
    ts[t] = s;
    __syncthreads();
    for (int off = 128; off >= 1; off >>= 1) {
        if (t < off) ts[t] += ts[t + off];
        __syncthreads();
    }
    if (t == 0) part[blockIdx.x] = ts[0];
}

__global__ void k_sser(int* part, int nb) {
    if (threadIdx.x == 0) {
        int run = 0;
        for (int b = 0; b < nb; ++b) { int v = part[b]; part[b] = run; run += v; }
    }
}

__global__ __launch_bounds__(256) void k_sscan(const int* __restrict__ a,
                                               const int* __restrict__ part,
                                               int* __restrict__ o, int M) {
    __shared__ int ts[256];
    int t = threadIdx.x;
    int g0 = blockIdx.x * 1024 + t * 4;
    int d[4];
    int s = 0;
#pragma unroll
    for (int i = 0; i < 4; ++i) {
        d[i] = (g0 + i < M) ? a[g0 + i] : 0;
        s += d[i];
    }
    ts[t] = s;
    __syncthreads();
    for (int off = 1; off < 256; off <<= 1) {
        int v = (t >= off) ? ts[t - off] : 0;
        __syncthreads();
        ts[t] += v;
        __syncthreads();
    }
    int run = part[blockIdx.x] + ts[t] - s;
#pragma unroll
    for (int i = 0; i < 4; ++i) {
        if (g0 + i < M) o[g0 + i] = run;
        run += d[i];
    }
}

// ---- Pass B: place packed (rowlocal<<17 | col) into bucket-ordered ebuf ----
__global__ __launch_bounds__(256) void k_binscatter(const int* __restrict__ row,
                                                    const int* __restrict__ col,
                                                    const int* __restrict__ histsc,
                                                    int* __restrict__ ebuf,
                                                    int E, int nbk, int per_blk) {
    __shared__ int cur[256];
    int t = threadIdx.x;
    cur[t] = (t < nbk) ? histsc[t * NBLK + blockIdx.x] : 0;
    __syncthreads();
    int s = blockIdx.x * per_blk;
    int e = min(s + per_blk, E);
    for (int i = s + t; i < e; i += 256) {
        int r = row[i];
        int b = r >> BKT_SHIFT;
        int p = atomicAdd(&cur[b], 1);
        ebuf[p] = ((r & (BKT_ROWS - 1)) << 17) | col[i];
    }
}

// ---- Pass C: per-bucket CSR build ----
__global__ __launch_bounds__(256) void k_build(const int* __restrict__ histsc,
                                               const int* __restrict__ ebuf,
                                               int* __restrict__ offs,
                                               int* __restrict__ scol,
                                               int N, int E, int nbk) {
    __shared__ int cnt[BKT_ROWS];
    __shared__ int loff[BKT_ROWS];
    __shared__ int ts[256];
    int b = blockIdx.x, t = threadIdx.x;
    int g0 = histsc[b * NBLK];
    int g1 = (b + 1 < nbk) ? histsc[(b + 1) * NBLK] : E;
    cnt[t] = 0;
    cnt[t + 256] = 0;
    __syncthreads();
    for (int i = g0 + t; i < g1; i += 256)
        atomicAdd(&cnt[((unsigned)ebuf[i]) >> 17], 1);
    __syncthreads();
    int c0 = cnt[2 * t], c1 = cnt[2 * t + 1];
    ts[t] = c0 + c1;
    __syncthreads();
    for (int off = 1; off < 256; off <<= 1) {
        int v = (t >= off) ? ts[t - off] : 0;
        __syncthreads();
        ts[t] += v;
        __syncthreads();
    }
    int ex = ts[t] - (c0 + c1);
    loff[2 * t] = ex;
    loff[2 * t + 1] = ex + c0;
    __syncthreads();
    int r0 = b << BKT_SHIFT;
    for (int r = t; r < BKT_ROWS; r += 256)
        if (r0 + r < N) offs[r0 + r] = g0 + loff[r];
    if (b == nbk - 1 && t == 0) offs[N] = E;
    cnt[t] = 0;
    cnt[t + 256] = 0;
    __syncthreads();
    for (int i = g0 + t; i < g1; i += 256) {
        unsigned v = (unsigned)ebuf[i];
        int rl = v >> 17;
        int c = (int)(v & 0x1FFFFu);
        int p = atomicAdd(&cnt[rl], 1);
        scol[g0 + loff[rl] + p] = c;
    }
}

// ---- fp32 -> fp16 table conversion ----
__global__ __launch_bounds__(256) void k_tohalf(const float* __restrict__ X,
                                                __half* __restrict__ XH, int M) {
    int idx = (blockIdx.x * 256 + threadIdx.x) * 4;
    if (idx < M) {
        float4 v = *(const float4*)(X + idx);
        union { __half2 h[2]; float2 f; } u;
        u.h[0] = __floats2half2_rn(v.x, v.y);
        u.h[1] = __floats2half2_rn(v.z, v.w);
        *(float2*)(XH + idx) = u.f;
    }
}

// ---- Mean-aggregate (fp16 in, fp32 out): one wave/node, half-wave/edge ----
__global__ __launch_bounds__(256) void k_agg(const __half2* __restrict__ X2,
                                             const int* __restrict__ offs,
                                             const int* __restrict__ scol,
                                             float* __restrict__ AGG, int N) {
    int node = blockIdx.x * 4 + (threadIdx.x >> 6);
    int lane = threadIdx.x & 63;
    if (node >= N) return;
    int s = offs[node], e = offs[node + 1];
    int c = lane & 31;
    float ax0 = 0.f, ay0 = 0.f, ax1 = 0.f, ay1 = 0.f;
    int j = s + (lane >> 5);
    for (; j + 2 < e; j += 4) {
        int n0 = scol[j], n1 = scol[j + 2];
        __half2 v0 = X2[n0 * 32 + c];
        __half2 v1 = X2[n1 * 32 + c];
        ax0 += __low2float(v0); ay0 += __high2float(v0);
        ax1 += __low2float(v1); ay1 += __high2float(v1);
    }
    if (j < e) {
        __half2 v = X2[scol[j] * 32 + c];
        ax0 += __low2float(v); ay0 += __high2float(v);
    }
    float ax = ax0 + ax1, ay = ay0 + ay1;
    ax += __shfl_down(ax, 32, 64);
    ay += __shfl_down(ay, 32, 64);
    if (lane < 32) {
        float inv = (e > s) ? 1.0f / (float)(e - s) : 1.0f;
        float2 r = {ax * inv, ay * inv};
        *(float2*)(AGG + node * CH + 2 * c) = r;
    }
}

// ---- h[n][o] = relu(cat(xh,agg)[n] . W[o] + b[o]); xh fp16, agg fp32 ----
__global__ __launch_bounds__(256) void k_gemm(const __half* __restrict__ A,
                                              const float* __restrict__ AGG,
                                              const float* __restrict__ W,
                                              const float* __restrict__ bias,
                                              __half* __restrict__ OUT, int N, int do_relu) {
    __shared__ float As[128][68];
    __shared__ float Ws[128][68];
    int t = threadIdx.x;
    int base = blockIdx.x * 64;

    {
        int o = t >> 2;
        int k0 = (t & 3) * 32;
        const float4* wr = (const float4*)(W + o * 128 + k0);
#pragma unroll
        for (int q = 0; q < 8; ++q) {
            float4 v = wr[q];
            Ws[k0 + q * 4 + 0][o] = v.x;
            Ws[k0 + q * 4 + 1][o] = v.y;
            Ws[k0 + q * 4 + 2][o] = v.z;
            Ws[k0 + q * 4 + 3][o] = v.w;
        }
    }
    {
        int n = t >> 2;
        int c0 = (t & 3) * 16;
        int gn = base + n;
        if (gn < N) {
            const float4* xr = (const float4*)(A + (size_t)gn * CH + c0);  // 8 halves per float4
            const float4* gr = (const float4*)(AGG + (size_t)gn * CH + c0);
#pragma unroll
            for (int q = 0; q < 2; ++q) {
                union { float4 f; __half2 h[4]; } u;
                u.f = xr[q];
#pragma unroll
                for (int p = 0; p < 4; ++p) {
                    As[c0 + q * 8 + 2 * p + 0][n] = __low2float(u.h[p]);
                    As[c0 + q * 8 + 2 * p + 1][n] = __high2float(u.h[p]);
                }
            }
#pragma unroll
            for (int q = 0; q < 4; ++q) {
                float4 g = gr[q];
                As[64 + c0 + q * 4 + 0][n] = g.x;
                As[64 + c0 + q * 4 + 1][n] = g.y;
                As[64 + c0 + q * 4 + 2][n] = g.z;
                As[64 + c0 + q * 4 + 3][n] = g.w;
            }
        } else {
#pragma unroll
            for (int i = 0; i < 16; ++i) {
                As[c0 + i][n] = 0.f;
                As[64 + c0 + i][n] = 0.f;
            }
        }
    }
    __syncthreads();

    int o0 = (t & 15) * 4;
    int n0 = (t >> 4) * 4;
    float acc[4][4];
#pragma unroll
    for (int i = 0; i < 4; ++i)
#pragma unroll
        for (int jj = 0; jj < 4; ++jj) acc[i][jj] = 0.f;

#pragma unroll 4
    for (int k = 0; k < 128; ++k) {
        float4 a = *(const float4*)&As[k][n0];
        float4 w = *(const float4*)&Ws[k][o0];
        acc[0][0] += a.x * w.x; acc[0][1] += a.x * w.y; acc[0][2] += a.x * w.z; acc[0][3] += a.x * w.w;
        acc[1][0] += a.y * w.x; acc[1][1] += a.y * w.y; acc[1][2] += a.y * w.z; acc[1][3] += a.y * w.w;
        acc[2][0] += a.z * w.x; acc[2][1] += a.z * w.y; acc[2][2] += a.z * w.z; acc[2][3] += a.z * w.w;
        acc[3][0] += a.w * w.x; acc[3][1] += a.w * w.y; acc[3][2] += a.w * w.z; acc[3][3] += a.w * w.w;
    }

    float4 bv = *(const float4*)&bias[o0];
#pragma unroll
    for (int i = 0; i < 4; ++i) {
        int gn = base + n0 + i;
        if (gn < N) {
            float rx = acc[i][0] + bv.x;
            float ry = acc[i][1] + bv.y;
            float rz = acc[i][2] + bv.z;
            float rw = acc[i][3] + bv.w;
            if (do_relu) {
                rx = fmaxf(rx, 0.f); ry = fmaxf(ry, 0.f);
                rz = fmaxf(rz, 0.f); rw = fmaxf(rw, 0.f);
            }
            union { __half2 h[2]; float2 f; } u;
            u.h[0] = __floats2half2_rn(rx, ry);
            u.h[1] = __floats2half2_rn(rz, rw);
            *(float2*)(OUT + (size_t)gn * CH + o0) = u.f;
        }
    }
}

// ---- Layer 3 fused: fp16 gather + [1,128] linear ----
__global__ __launch_bounds__(256) void k_final(const __half2* __restrict__ H2,
                                               const int* __restrict__ offs,
                                               const int* __restrict__ scol,
                                               const float* __restrict__ W3,
                                               const float* __restrict__ b3,
                                               float* __restrict__ out, int N) {
    int node = blockIdx.x * 4 + (threadIdx.x >> 6);
    int lane = threadIdx.x & 63;
    if (node >= N) return;
    int s = offs[node], e = offs[node + 1];
    int c = lane & 31;
    float ax0 = 0.f, ay0 = 0.f, ax1 = 0.f, ay1 = 0.f;
    int j = s + (lane >> 5);
    for (; j + 2 < e; j += 4) {
        int n0 = scol[j], n1 = scol[j + 2];
        __half2 v0 = H2[n0 * 32 + c];
        __half2 v1 = H2[n1 * 32 + c];
        ax0 += __low2float(v0); ay0 += __high2float(v0);
        ax1 += __low2float(v1); ay1 += __high2float(v1);
    }
    if (j < e) {
        __half2 v = H2[scol[j] * 32 + c];
        ax0 += __low2float(v); ay0 += __high2float(v);
    }
    float ax = ax0 + ax1, ay = ay0 + ay1;
    ax += __shfl_down(ax, 32, 64);
    ay += __shfl_down(ay, 32, 64);
    if (lane < 32) {
        float inv = (e > s) ? 1.0f / (float)(e - s) : 1.0f;
        __half2 self = H2[node * 32 + c];
        float v = __low2float(self) * W3[2 * c] + __high2float(self) * W3[2 * c + 1]
                + ax * inv * W3[64 + 2 * c] + ay * inv * W3[64 + 2 * c + 1];
#pragma unroll
        for (int off = 16; off >= 1; off >>= 1) v += __shfl_down(v, off, 64);
        if (lane == 0) out[node] = v + b3[0];
    }
}

extern "C" void kernel_launch(void* const* d_in, const int* in_sizes, int n_in,
                              void* d_out, int out_size, void* d_ws, size_t ws_size,
                              hipStream_t stream) {
    const float* x   = (const float*)d_in[0];
    const int* eidx  = (const int*)d_in[1];
    const float* W1  = (const float*)d_in[2];
    const float* b1  = (const float*)d_in[3];
    const float* W2  = (const float*)d_in[4];
    const float* b2  = (const float*)d_in[5];
    const float* W3  = (const float*)d_in[6];
    const float* b3  = (const float*)d_in[7];
    float* out = (float*)d_out;

    const int N = in_sizes[0] / CH;
    const int E = in_sizes[1] / 2;
    const int* row = eidx;
    const int* col = eidx + E;

    int offs_sz = ((N + 1 + 3) / 4) * 4;
    int e_sz    = ((E + 3) / 4) * 4;

    int* offs  = (int*)d_ws;                       // offs_sz
    int* scol  = offs + offs_sz;                   // e_sz
    __half* xh = (__half*)(scol + e_sz);           // N*64 halves
    __half* h1 = xh + (size_t)N * CH;
    __half* h2 = h1 + (size_t)N * CH;
    float* agg = (float*)(h2 + (size_t)N * CH);    // N*64 floats
    // sort scratch aliases agg region (agg first written after sort is done)
    int* ebuf   = (int*)agg;                       // E
    int nbk     = (N + BKT_ROWS - 1) >> BKT_SHIFT;
    int* hist   = ebuf + e_sz;                     // nbk*NBLK
    int* histsc = hist + (size_t)nbk * NBLK;
    int* part   = histsc + (size_t)nbk * NBLK;     // 64

    int M = nbk * NBLK;
    int per_blk = (E + NBLK - 1) / NBLK;
    int mb = (M + 1023) / 1024;
    int abl = (N + 3) / 4;
    int gbl = (N + 63) / 64;
    int cvb = (N * CH / 4 + 255) / 256;

    // CSR build
    k_hist<<<NBLK, 256, 0, stream>>>(row, hist, E, nbk, per_blk);
    k_ssum<<<mb, 256, 0, stream>>>(hist, part, M);
    k_sser<<<1, 64, 0, stream>>>(part, mb);
    k_sscan<<<mb, 256, 0, stream>>>(hist, part, histsc, M);
    k_binscatter<<<NBLK, 256, 0, stream>>>(row, col, histsc, ebuf, E, nbk, per_blk);
    k_build<<<nbk, 256, 0, stream>>>(histsc, ebuf, offs, scol, N, E, nbk);

    // x -> fp16 table
    k_tohalf<<<cvb, 256, 0, stream>>>(x, xh, N * CH);

    // layer 1
    k_agg<<<abl, 256, 0, stream>>>((const __half2*)xh, offs, scol, agg, N);
    k_gemm<<<gbl, 256, 0, stream>>>(xh, agg, W1, b1, h1, N, 1);
    // layer 2
    k_agg<<<abl, 256, 0, stream>>>((const __half2*)h1, offs, scol, agg, N);
    k_gemm<<<gbl, 256, 0, stream>>>(h1, agg, W2, b2, h2, N, 1);
    // layer 3
    k_final<<<abl, 256, 0, stream>>>((const __half2*)h2, offs, scol, W3, b3, out, N);
}

// Round 4
// 358.011 us; speedup vs baseline: 1.5785x; 1.1083x over previous
//
#include <hip/hip_runtime.h>
#include <hip/hip_fp16.h>

// GraphSAGE 3-layer. CSR via two-level counting sort. fp16 feature tables.
// Gather: 8 lanes/edge, float4(8 fp16)/lane, 16 edges in flight per wave.
//
// ws: offs[N+1] | scol[E] | xh h[N*64] | h1 h[N*64] | h2 h[N*64] | agg f[N*64]
//     (sort scratch ebuf/hist/histsc/part aliases the agg region)

#define CH 64
#define BKT_SHIFT 9
#define BKT_ROWS 512
#define NBLK 256  // pass A/B blocks; requires nbk <= 256 (N <= 131072)

// ---- Pass A: per-block bucket histogram, layout hist[bucket][NBLK] ----
__global__ __launch_bounds__(256) void k_hist(const int* __restrict__ row,
                                              int* __restrict__ hist,
                                              int E, int nbk, int per_blk) {
    __shared__ int h[256];
    int t = threadIdx.x;
    h[t] = 0;
    __syncthreads();
    int s = blockIdx.x * per_blk;
    int e = min(s + per_blk, E);
    for (int i = s + t; i < e; i += 256)
        atomicAdd(&h[row[i] >> BKT_SHIFT], 1);
    __syncthreads();
    if (t < nbk) hist[t * NBLK + blockIdx.x] = h[t];
}

// ---- generic 3-kernel exclusive scan over M ints ----
__global__ __launch_bounds__(256) void k_ssum(const int* __restrict__ a,
                                              int* __restrict__ part, int M) {
    __shared__ int ts[256];
    int t = threadIdx.x;
    int g0 = blockIdx.x * 1024 + t * 4;
    int s = 0;
#pragma unroll
    for (int i = 0; i < 4; ++i)
        if (g0 + i < M) s += a[g0 + i];
    ts[t] = s;
    __syncthreads();
    for (int off = 128; off >= 1; off >>= 1) {
        if (t < off) ts[t] += ts[t + off];
        __syncthreads();
    }
    if (t == 0) part[blockIdx.x] = ts[0];
}

__global__ void k_sser(int* part, int nb) {
    if (threadIdx.x == 0) {
        int run = 0;
        for (int b = 0; b < nb; ++b) { int v = part[b]; part[b] = run; run += v; }
    }
}

__global__ __launch_bounds__(256) void k_sscan(const int* __restrict__ a,
                                               const int* __restrict__ part,
                                               int* __restrict__ o, int M) {
    __shared__ int ts[256];
    int t = threadIdx.x;
    int g0 = blockIdx.x * 1024 + t * 4;
    int d[4];
    int s = 0;
#pragma unroll
    for (int i = 0; i < 4; ++i) {
        d[i] = (g0 + i < M) ? a[g0 + i] : 0;
        s += d[i];
    }
    ts[t] = s;
    __syncthreads();
    for (int off = 1; off < 256; off <<= 1) {
        int v = (t >= off) ? ts[t - off] : 0;
        __syncthreads();
        ts[t] += v;
        __syncthreads();
    }
    int run = part[blockIdx.x] + ts[t] - s;
#pragma unroll
    for (int i = 0; i < 4; ++i) {
        if (g0 + i < M) o[g0 + i] = run;
        run += d[i];
    }
}

// ---- Pass B: place packed (rowlocal<<17 | col) into bucket-ordered ebuf ----
__global__ __launch_bounds__(256) void k_binscatter(const int* __restrict__ row,
                                                    const int* __restrict__ col,
                                                    const int* __restrict__ histsc,
                                                    int* __restrict__ ebuf,
                                                    int E, int nbk, int per_blk) {
    __shared__ int cur[256];
    int t = threadIdx.x;
    cur[t] = (t < nbk) ? histsc[t * NBLK + blockIdx.x] : 0;
    __syncthreads();
    int s = blockIdx.x * per_blk;
    int e = min(s + per_blk, E);
    for (int i = s + t; i < e; i += 256) {
        int r = row[i];
        int b = r >> BKT_SHIFT;
        int p = atomicAdd(&cur[b], 1);
        ebuf[p] = ((r & (BKT_ROWS - 1)) << 17) | col[i];
    }
}

// ---- Pass C: per-bucket CSR build ----
__global__ __launch_bounds__(256) void k_build(const int* __restrict__ histsc,
                                               const int* __restrict__ ebuf,
                                               int* __restrict__ offs,
                                               int* __restrict__ scol,
                                               int N, int E, int nbk) {
    __shared__ int cnt[BKT_ROWS];
    __shared__ int loff[BKT_ROWS];
    __shared__ int ts[256];
    int b = blockIdx.x, t = threadIdx.x;
    int g0 = histsc[b * NBLK];
    int g1 = (b + 1 < nbk) ? histsc[(b + 1) * NBLK] : E;
    cnt[t] = 0;
    cnt[t + 256] = 0;
    __syncthreads();
    for (int i = g0 + t; i < g1; i += 256)
        atomicAdd(&cnt[((unsigned)ebuf[i]) >> 17], 1);
    __syncthreads();
    int c0 = cnt[2 * t], c1 = cnt[2 * t + 1];
    ts[t] = c0 + c1;
    __syncthreads();
    for (int off = 1; off < 256; off <<= 1) {
        int v = (t >= off) ? ts[t - off] : 0;
        __syncthreads();
        ts[t] += v;
        __syncthreads();
    }
    int ex = ts[t] - (c0 + c1);
    loff[2 * t] = ex;
    loff[2 * t + 1] = ex + c0;
    __syncthreads();
    int r0 = b << BKT_SHIFT;
    for (int r = t; r < BKT_ROWS; r += 256)
        if (r0 + r < N) offs[r0 + r] = g0 + loff[r];
    if (b == nbk - 1 && t == 0) offs[N] = E;
    cnt[t] = 0;
    cnt[t + 256] = 0;
    __syncthreads();
    for (int i = g0 + t; i < g1; i += 256) {
        unsigned v = (unsigned)ebuf[i];
        int rl = v >> 17;
        int c = (int)(v & 0x1FFFFu);
        int p = atomicAdd(&cnt[rl], 1);
        scol[g0 + loff[rl] + p] = c;
    }
}

// ---- fp32 -> fp16 table conversion ----
__global__ __launch_bounds__(256) void k_tohalf(const float* __restrict__ X,
                                                __half* __restrict__ XH, int M) {
    int idx = (blockIdx.x * 256 + threadIdx.x) * 4;
    if (idx < M) {
        float4 v = *(const float4*)(X + idx);
        union { __half2 h[2]; float2 f; } u;
        u.h[0] = __floats2half2_rn(v.x, v.y);
        u.h[1] = __floats2half2_rn(v.z, v.w);
        *(float2*)(XH + idx) = u.f;
    }
}

// ---- Mean-aggregate: one wave/node, 8 lanes/edge, float4(8 fp16)/lane ----
__global__ __launch_bounds__(256) void k_agg(const float4* __restrict__ X4,
                                             const int* __restrict__ offs,
                                             const int* __restrict__ scol,
                                             float* __restrict__ AGG, int N) {
    int node = blockIdx.x * 4 + (threadIdx.x >> 6);
    int lane = threadIdx.x & 63;
    if (node >= N) return;
    int s = offs[node], e = offs[node + 1];
    int sub = lane & 7;   // which 16B chunk (8 halves) of the 128B row
    int grp = lane >> 3;  // edge slot 0..7
    float a[8];
#pragma unroll
    for (int k = 0; k < 8; ++k) a[k] = 0.f;
    int j = s + grp;
    for (; j + 8 < e; j += 16) {
        float4 r0 = X4[(size_t)scol[j] * 8 + sub];
        float4 r1 = X4[(size_t)scol[j + 8] * 8 + sub];
        const __half2* h0 = (const __half2*)&r0;
        const __half2* h1 = (const __half2*)&r1;
#pragma unroll
        for (int p = 0; p < 4; ++p) {
            float2 f0 = __half22float2(h0[p]);
            float2 f1 = __half22float2(h1[p]);
            a[2 * p]     += f0.x + f1.x;
            a[2 * p + 1] += f0.y + f1.y;
        }
    }
    if (j < e) {
        float4 r0 = X4[(size_t)scol[j] * 8 + sub];
        const __half2* h0 = (const __half2*)&r0;
#pragma unroll
        for (int p = 0; p < 4; ++p) {
            float2 f0 = __half22float2(h0[p]);
            a[2 * p]     += f0.x;
            a[2 * p + 1] += f0.y;
        }
    }
#pragma unroll
    for (int off = 32; off >= 8; off >>= 1)
#pragma unroll
        for (int k = 0; k < 8; ++k)
            a[k] += __shfl_down(a[k], off, 64);
    if (lane < 8) {
        float inv = (e > s) ? 1.0f / (float)(e - s) : 1.0f;
        float4* dst = (float4*)(AGG + (size_t)node * CH + sub * 8);
        float4 w0 = {a[0] * inv, a[1] * inv, a[2] * inv, a[3] * inv};
        float4 w1 = {a[4] * inv, a[5] * inv, a[6] * inv, a[7] * inv};
        dst[0] = w0;
        dst[1] = w1;
    }
}

// ---- h[n][o] = relu(cat(xh,agg)[n] . W[o] + b[o]); xh fp16, agg fp32 ----
__global__ __launch_bounds__(256) void k_gemm(const __half* __restrict__ A,
                                              const float* __restrict__ AGG,
                                              const float* __restrict__ W,
                                              const float* __restrict__ bias,
                                              __half* __restrict__ OUT, int N, int do_relu) {
    __shared__ float As[128][68];
    __shared__ float Ws[128][68];
    int t = threadIdx.x;
    int base = blockIdx.x * 64;

    {
        int o = t >> 2;
        int k0 = (t & 3) * 32;
        const float4* wr = (const float4*)(W + o * 128 + k0);
#pragma unroll
        for (int q = 0; q < 8; ++q) {
            float4 v = wr[q];
            Ws[k0 + q * 4 + 0][o] = v.x;
            Ws[k0 + q * 4 + 1][o] = v.y;
            Ws[k0 + q * 4 + 2][o] = v.z;
            Ws[k0 + q * 4 + 3][o] = v.w;
        }
    }
    {
        int n = t >> 2;
        int c0 = (t & 3) * 16;
        int gn = base + n;
        if (gn < N) {
            const float4* xr = (const float4*)(A + (size_t)gn * CH + c0);
            const float4* gr = (const float4*)(AGG + (size_t)gn * CH + c0);
#pragma unroll
            for (int q = 0; q < 2; ++q) {
                union { float4 f; __half2 h[4]; } u;
                u.f = xr[q];
#pragma unroll
                for (int p = 0; p < 4; ++p) {
                    As[c0 + q * 8 + 2 * p + 0][n] = __low2float(u.h[p]);
                    As[c0 + q * 8 + 2 * p + 1][n] = __high2float(u.h[p]);
                }
            }
#pragma unroll
            for (int q = 0; q < 4; ++q) {
                float4 g = gr[q];
                As[64 + c0 + q * 4 + 0][n] = g.x;
                As[64 + c0 + q * 4 + 1][n] = g.y;
                As[64 + c0 + q * 4 + 2][n] = g.z;
                As[64 + c0 + q * 4 + 3][n] = g.w;
            }
        } else {
#pragma unroll
            for (int i = 0; i < 16; ++i) {
                As[c0 + i][n] = 0.f;
                As[64 + c0 + i][n] = 0.f;
            }
        }
    }
    __syncthreads();

    int o0 = (t & 15) * 4;
    int n0 = (t >> 4) * 4;
    float acc[4][4];
#pragma unroll
    for (int i = 0; i < 4; ++i)
#pragma unroll
        for (int jj = 0; jj < 4; ++jj) acc[i][jj] = 0.f;

#pragma unroll 4
    for (int k = 0; k < 128; ++k) {
        float4 a = *(const float4*)&As[k][n0];
        float4 w = *(const float4*)&Ws[k][o0];
        acc[0][0] += a.x * w.x; acc[0][1] += a.x * w.y; acc[0][2] += a.x * w.z; acc[0][3] += a.x * w.w;
        acc[1][0] += a.y * w.x; acc[1][1] += a.y * w.y; acc[1][2] += a.y * w.z; acc[1][3] += a.y * w.w;
        acc[2][0] += a.z * w.x; acc[2][1] += a.z * w.y; acc[2][2] += a.z * w.z; acc[2][3] += a.z * w.w;
        acc[3][0] += a.w * w.x; acc[3][1] += a.w * w.y; acc[3][2] += a.w * w.z; acc[3][3] += a.w * w.w;
    }

    float4 bv = *(const float4*)&bias[o0];
#pragma unroll
    for (int i = 0; i < 4; ++i) {
        int gn = base + n0 + i;
        if (gn < N) {
            float rx = acc[i][0] + bv.x;
            float ry = acc[i][1] + bv.y;
            float rz = acc[i][2] + bv.z;
            float rw = acc[i][3] + bv.w;
            if (do_relu) {
                rx = fmaxf(rx, 0.f); ry = fmaxf(ry, 0.f);
                rz = fmaxf(rz, 0.f); rw = fmaxf(rw, 0.f);
            }
            union { __half2 h[2]; float2 f; } u;
            u.h[0] = __floats2half2_rn(rx, ry);
            u.h[1] = __floats2half2_rn(rz, rw);
            *(float2*)(OUT + (size_t)gn * CH + o0) = u.f;
        }
    }
}

// ---- Layer 3 fused: gather (8 lanes/edge) + [1,128] linear ----
__global__ __launch_bounds__(256) void k_final(const float4* __restrict__ H4,
                                               const int* __restrict__ offs,
                                               const int* __restrict__ scol,
                                               const float* __restrict__ W3,
                                               const float* __restrict__ b3,
                                               float* __restrict__ out, int N) {
    int node = blockIdx.x * 4 + (threadIdx.x >> 6);
    int lane = threadIdx.x & 63;
    if (node >= N) return;
    int s = offs[node], e = offs[node + 1];
    int sub = lane & 7;
    int grp = lane >> 3;
    float a[8];
#pragma unroll
    for (int k = 0; k < 8; ++k) a[k] = 0.f;
    int j = s + grp;
    for (; j + 8 < e; j += 16) {
        float4 r0 = H4[(size_t)scol[j] * 8 + sub];
        float4 r1 = H4[(size_t)scol[j + 8] * 8 + sub];
        const __half2* h0 = (const __half2*)&r0;
        const __half2* h1 = (const __half2*)&r1;
#pragma unroll
        for (int p = 0; p < 4; ++p) {
            float2 f0 = __half22float2(h0[p]);
            float2 f1 = __half22float2(h1[p]);
            a[2 * p]     += f0.x + f1.x;
            a[2 * p + 1] += f0.y + f1.y;
        }
    }
    if (j < e) {
        float4 r0 = H4[(size_t)scol[j] * 8 + sub];
        const __half2* h0 = (const __half2*)&r0;
#pragma unroll
        for (int p = 0; p < 4; ++p) {
            float2 f0 = __half22float2(h0[p]);
            a[2 * p]     += f0.x;
            a[2 * p + 1] += f0.y;
        }
    }
#pragma unroll
    for (int off = 32; off >= 8; off >>= 1)
#pragma unroll
        for (int k = 0; k < 8; ++k)
            a[k] += __shfl_down(a[k], off, 64);
    if (lane < 8) {
        float inv = (e > s) ? 1.0f / (float)(e - s) : 1.0f;
        float4 self = H4[(size_t)node * 8 + sub];
        const __half2* sh = (const __half2*)&self;
        const float4* w = (const float4*)W3;
        float4 ws0 = w[sub * 2],      ws1 = w[sub * 2 + 1];
        float4 wa0 = w[16 + sub * 2], wa1 = w[17 + sub * 2];
        float2 s0 = __half22float2(sh[0]), s1 = __half22float2(sh[1]);
        float2 s2 = __half22float2(sh[2]), s3 = __half22float2(sh[3]);
        float v = s0.x * ws0.x + s0.y * ws0.y + s1.x * ws0.z + s1.y * ws0.w
                + s2.x * ws1.x + s2.y * ws1.y + s3.x * ws1.z + s3.y * ws1.w
                + inv * (a[0] * wa0.x + a[1] * wa0.y + a[2] * wa0.z + a[3] * wa0.w
                       + a[4] * wa1.x + a[5] * wa1.y + a[6] * wa1.z + a[7] * wa1.w);
        v += __shfl_down(v, 4, 64);
        v += __shfl_down(v, 2, 64);
        v += __shfl_down(v, 1, 64);
        if (lane == 0) out[node] = v + b3[0];
    }
}

extern "C" void kernel_launch(void* const* d_in, const int* in_sizes, int n_in,
                              void* d_out, int out_size, void* d_ws, size_t ws_size,
                              hipStream_t stream) {
    const float* x   = (const float*)d_in[0];
    const int* eidx  = (const int*)d_in[1];
    const float* W1  = (const float*)d_in[2];
    const float* b1  = (const float*)d_in[3];
    const float* W2  = (const float*)d_in[4];
    const float* b2  = (const float*)d_in[5];
    const float* W3  = (const float*)d_in[6];
    const float* b3  = (const float*)d_in[7];
    float* out = (float*)d_out;

    const int N = in_sizes[0] / CH;
    const int E = in_sizes[1] / 2;
    const int* row = eidx;
    const int* col = eidx + E;

    int offs_sz = ((N + 1 + 3) / 4) * 4;
    int e_sz    = ((E + 3) / 4) * 4;

    int* offs  = (int*)d_ws;                       // offs_sz
    int* scol  = offs + offs_sz;                   // e_sz
    __half* xh = (__half*)(scol + e_sz);           // N*64 halves
    __half* h1 = xh + (size_t)N * CH;
    __half* h2 = h1 + (size_t)N * CH;
    float* agg = (float*)(h2 + (size_t)N * CH);    // N*64 floats
    // sort scratch aliases agg region (agg first written after sort is done)
    int* ebuf   = (int*)agg;                       // E
    int nbk     = (N + BKT_ROWS - 1) >> BKT_SHIFT;
    int* hist   = ebuf + e_sz;                     // nbk*NBLK
    int* histsc = hist + (size_t)nbk * NBLK;
    int* part   = histsc + (size_t)nbk * NBLK;     // 64

    int M = nbk * NBLK;
    int per_blk = (E + NBLK - 1) / NBLK;
    int mb = (M + 1023) / 1024;
    int abl = (N + 3) / 4;
    int gbl = (N + 63) / 64;
    int cvb = (N * CH / 4 + 255) / 256;

    // CSR build
    k_hist<<<NBLK, 256, 0, stream>>>(row, hist, E, nbk, per_blk);
    k_ssum<<<mb, 256, 0, stream>>>(hist, part, M);
    k_sser<<<1, 64, 0, stream>>>(part, mb);
    k_sscan<<<mb, 256, 0, stream>>>(hist, part, histsc, M);
    k_binscatter<<<NBLK, 256, 0, stream>>>(row, col, histsc, ebuf, E, nbk, per_blk);
    k_build<<<nbk, 256, 0, stream>>>(histsc, ebuf, offs, scol, N, E, nbk);

    // x -> fp16 table
    k_tohalf<<<cvb, 256, 0, stream>>>(x, xh, N * CH);

    // layer 1
    k_agg<<<abl, 256, 0, stream>>>((const float4*)xh, offs, scol, agg, N);
    k_gemm<<<gbl, 256, 0, stream>>>(xh, agg, W1, b1, h1, N, 1);
    // layer 2
    k_agg<<<abl, 256, 0, stream>>>((const float4*)h1, offs, scol, agg, N);
    k_gemm<<<gbl, 256, 0, stream>>>(h1, agg, W2, b2, h2, N, 1);
    // layer 3
    k_final<<<abl, 256, 0, stream>>>((const float4*)h2, offs, scol, W3, b3, out, N);
}

// Round 5
// 319.235 us; speedup vs baseline: 1.7703x; 1.1215x over previous
//
#include <hip/hip_runtime.h>
#include <hip/hip_fp16.h>

// GraphSAGE 3-layer. CSR via two-level counting sort. fp16 feature tables
// (N+1 rows; row N is a zero row used to make gather prefetch branchless).
// Layer-3 reduced to per-node scalar dots + 4B/edge gather (OUT_CH==1).
//
// ws: offs[N+1] | scol[E] | xh h[(N+1)*64] | h1 | h2 | agg f[N*64]
//     (sort scratch ebuf/hist/histsc aliases agg region; tarr/sarr also
//      alias agg region — agg is dead after layer-2 GEMM)

#define CH 64
#define BKT_SHIFT 9
#define BKT_ROWS 512
#define NBLK 256  // pass A/B blocks; requires nbk <= 256 (N <= 131072)

// ---- Pass A: per-block bucket histogram, layout hist[bucket][NBLK] ----
__global__ __launch_bounds__(256) void k_hist(const int* __restrict__ row,
                                              int* __restrict__ hist,
                                              int E, int nbk, int per_blk) {
    __shared__ int h[256];
    int t = threadIdx.x;
    h[t] = 0;
    __syncthreads();
    int s = blockIdx.x * per_blk;
    int e = min(s + per_blk, E);
    for (int i = s + t; i < e; i += 256)
        atomicAdd(&h[row[i] >> BKT_SHIFT], 1);
    __syncthreads();
    if (t < nbk) hist[t * NBLK + blockIdx.x] = h[t];
}

// ---- generic 3-kernel exclusive scan over M ints ----
__global__ __launch_bounds__(256) void k_ssum(const int* __restrict__ a,
                                              int* __restrict__ part, int M) {
    __shared__ int ts[256];
    int t = threadIdx.x;
    int g0 = blockIdx.x * 1024 + t * 4;
    int s = 0;
#pragma unroll
    for (int i = 0; i < 4; ++i)
        if (g0 + i < M) s += a[g0 + i];
    ts[t] = s;
    __syncthreads();
    for (int off = 128; off >= 1; off >>= 1) {
        if (t < off) ts[t] += ts[t + off];
        __syncthreads();
    }
    if (t == 0) part[blockIdx.x] = ts[0];
}

__global__ void k_sser(int* part, int nb) {
    if (threadIdx.x == 0) {
        int run = 0;
        for (int b = 0; b < nb; ++b) { int v = part[b]; part[b] = run; run += v; }
    }
}

__global__ __launch_bounds__(256) void k_sscan(const int* __restrict__ a,
                                               const int* __restrict__ part,
                                               int* __restrict__ o, int M) {
    __shared__ int ts[256];
    int t = threadIdx.x;
    int g0 = blockIdx.x * 1024 + t * 4;
    int d[4];
    int s = 0;
#pragma unroll
    for (int i = 0; i < 4; ++i) {
        d[i] = (g0 + i < M) ? a[g0 + i] : 0;
        s += d[i];
    }
    ts[t] = s;
    __syncthreads();
    for (int off = 1; off < 256; off <<= 1) {
        int v = (t >= off) ? ts[t - off] : 0;
        __syncthreads();
        ts[t] += v;
        __syncthreads();
    }
    int run = part[blockIdx.x] + ts[t] - s;
#pragma unroll
    for (int i = 0; i < 4; ++i) {
        if (g0 + i < M) o[g0 + i] = run;
        run += d[i];
    }
}

// ---- Pass B: place packed (rowlocal<<17 | col) into bucket-ordered ebuf ----
__global__ __launch_bounds__(256) void k_binscatter(const int* __restrict__ row,
                                                    const int* __restrict__ col,
                                                    const int* __restrict__ histsc,
                                                    int* __restrict__ ebuf,
                                                    int E, int nbk, int per_blk) {
    __shared__ int cur[256];
    int t = threadIdx.x;
    cur[t] = (t < nbk) ? histsc[t * NBLK + blockIdx.x] : 0;
    __syncthreads();
    int s = blockIdx.x * per_blk;
    int e = min(s + per_blk, E);
    for (int i = s + t; i < e; i += 256) {
        int r = row[i];
        int b = r >> BKT_SHIFT;
        int p = atomicAdd(&cur[b], 1);
        ebuf[p] = ((r & (BKT_ROWS - 1)) << 17) | col[i];
    }
}

// ---- Pass C: per-bucket CSR build ----
__global__ __launch_bounds__(256) void k_build(const int* __restrict__ histsc,
                                               const int* __restrict__ ebuf,
                                               int* __restrict__ offs,
                                               int* __restrict__ scol,
                                               int N, int E, int nbk) {
    __shared__ int cnt[BKT_ROWS];
    __shared__ int loff[BKT_ROWS];
    __shared__ int ts[256];
    int b = blockIdx.x, t = threadIdx.x;
    int g0 = histsc[b * NBLK];
    int g1 = (b + 1 < nbk) ? histsc[(b + 1) * NBLK] : E;
    cnt[t] = 0;
    cnt[t + 256] = 0;
    __syncthreads();
    for (int i = g0 + t; i < g1; i += 256)
        atomicAdd(&cnt[((unsigned)ebuf[i]) >> 17], 1);
    __syncthreads();
    int c0 = cnt[2 * t], c1 = cnt[2 * t + 1];
    ts[t] = c0 + c1;
    __syncthreads();
    for (int off = 1; off < 256; off <<= 1) {
        int v = (t >= off) ? ts[t - off] : 0;
        __syncthreads();
        ts[t] += v;
        __syncthreads();
    }
    int ex = ts[t] - (c0 + c1);
    loff[2 * t] = ex;
    loff[2 * t + 1] = ex + c0;
    __syncthreads();
    int r0 = b << BKT_SHIFT;
    for (int r = t; r < BKT_ROWS; r += 256)
        if (r0 + r < N) offs[r0 + r] = g0 + loff[r];
    if (b == nbk - 1 && t == 0) offs[N] = E;
    cnt[t] = 0;
    cnt[t + 256] = 0;
    __syncthreads();
    for (int i = g0 + t; i < g1; i += 256) {
        unsigned v = (unsigned)ebuf[i];
        int rl = v >> 17;
        int c = (int)(v & 0x1FFFFu);
        int p = atomicAdd(&cnt[rl], 1);
        scol[g0 + loff[rl] + p] = c;
    }
}

// ---- fp32 -> fp16 table conversion ----
__global__ __launch_bounds__(256) void k_tohalf(const float* __restrict__ X,
                                                __half* __restrict__ XH, int M) {
    int idx = (blockIdx.x * 256 + threadIdx.x) * 4;
    if (idx < M) {
        float4 v = *(const float4*)(X + idx);
        union { __half2 h[2]; float2 f; } u;
        u.h[0] = __floats2half2_rn(v.x, v.y);
        u.h[1] = __floats2half2_rn(v.z, v.w);
        *(float2*)(XH + idx) = u.f;
    }
}

// ---- zero row N of the three fp16 tables (dummy row for clamped loads) ----
__global__ void k_zrow(float4* xh4, float4* h14, float4* h24, int N) {
    int t = threadIdx.x;
    float4 z = {0.f, 0.f, 0.f, 0.f};
    if (t < 8) xh4[(size_t)N * 8 + t] = z;
    else if (t < 16) h14[(size_t)N * 8 + (t - 8)] = z;
    else if (t < 24) h24[(size_t)N * 8 + (t - 16)] = z;
}

// ---- Mean-aggregate: one wave/node, 8 lanes/edge, 4 chunk-loads in flight.
//      Invalid slots clamp to zero-row N (branchless). ----
__global__ __launch_bounds__(256) void k_agg(const float4* __restrict__ X4,
                                             const int* __restrict__ offs,
                                             const int* __restrict__ scol,
                                             float* __restrict__ AGG, int N, int Em1) {
    int node = blockIdx.x * 4 + (threadIdx.x >> 6);
    int lane = threadIdx.x & 63;
    if (node >= N) return;
    int s = offs[node], e = offs[node + 1];
    int sub = lane & 7;   // 16B chunk of the 128B row
    int grp = lane >> 3;  // edge slot 0..7
    int j = s + grp;
    // 4 prefetched chunk loads, clamped to safe scol index / zero row
    int i0 = scol[min(j, Em1)];       i0 = (j < e)      ? i0 : N;
    int i1 = scol[min(j + 8, Em1)];   i1 = (j + 8 < e)  ? i1 : N;
    int i2 = scol[min(j + 16, Em1)];  i2 = (j + 16 < e) ? i2 : N;
    int i3 = scol[min(j + 24, Em1)];  i3 = (j + 24 < e) ? i3 : N;
    float4 r0 = X4[(size_t)i0 * 8 + sub];
    float4 r1 = X4[(size_t)i1 * 8 + sub];
    float4 r2 = X4[(size_t)i2 * 8 + sub];
    float4 r3 = X4[(size_t)i3 * 8 + sub];
    float a[8];
#pragma unroll
    for (int k = 0; k < 8; ++k) a[k] = 0.f;
    {
        const __half2* h0 = (const __half2*)&r0;
        const __half2* h1 = (const __half2*)&r1;
        const __half2* h2 = (const __half2*)&r2;
        const __half2* h3 = (const __half2*)&r3;
#pragma unroll
        for (int p = 0; p < 4; ++p) {
            float2 f0 = __half22float2(h0[p]);
            float2 f1 = __half22float2(h1[p]);
            float2 f2 = __half22float2(h2[p]);
            float2 f3 = __half22float2(h3[p]);
            a[2 * p]     += (f0.x + f1.x) + (f2.x + f3.x);
            a[2 * p + 1] += (f0.y + f1.y) + (f2.y + f3.y);
        }
    }
    // rare tail: deg > 32
    for (j += 32; j < e; j += 8) {
        float4 r = X4[(size_t)scol[j] * 8 + sub];
        const __half2* h = (const __half2*)&r;
#pragma unroll
        for (int p = 0; p < 4; ++p) {
            float2 f = __half22float2(h[p]);
            a[2 * p]     += f.x;
            a[2 * p + 1] += f.y;
        }
    }
#pragma unroll
    for (int off = 32; off >= 8; off >>= 1)
#pragma unroll
        for (int k = 0; k < 8; ++k)
            a[k] += __shfl_down(a[k], off, 64);
    if (lane < 8) {
        float inv = (e > s) ? 1.0f / (float)(e - s) : 1.0f;
        float4* dst = (float4*)(AGG + (size_t)node * CH + sub * 8);
        float4 w0 = {a[0] * inv, a[1] * inv, a[2] * inv, a[3] * inv};
        float4 w1 = {a[4] * inv, a[5] * inv, a[6] * inv, a[7] * inv};
        dst[0] = w0;
        dst[1] = w1;
    }
}

// ---- h[n][o] = relu(cat(xh,agg)[n] . W[o] + b[o]); xh fp16, agg fp32 ----
__global__ __launch_bounds__(256) void k_gemm(const __half* __restrict__ A,
                                              const float* __restrict__ AGG,
                                              const float* __restrict__ W,
                                              const float* __restrict__ bias,
                                              __half* __restrict__ OUT, int N, int do_relu) {
    __shared__ float As[128][68];
    __shared__ float Ws[128][68];
    int t = threadIdx.x;
    int base = blockIdx.x * 64;

    {
        int o = t >> 2;
        int k0 = (t & 3) * 32;
        const float4* wr = (const float4*)(W + o * 128 + k0);
#pragma unroll
        for (int q = 0; q < 8; ++q) {
            float4 v = wr[q];
            Ws[k0 + q * 4 + 0][o] = v.x;
            Ws[k0 + q * 4 + 1][o] = v.y;
            Ws[k0 + q * 4 + 2][o] = v.z;
            Ws[k0 + q * 4 + 3][o] = v.w;
        }
    }
    {
        int n = t >> 2;
        int c0 = (t & 3) * 16;
        int gn = base + n;
        if (gn < N) {
            const float4* xr = (const float4*)(A + (size_t)gn * CH + c0);
            const float4* gr = (const float4*)(AGG + (size_t)gn * CH + c0);
#pragma unroll
            for (int q = 0; q < 2; ++q) {
                union { float4 f; __half2 h[4]; } u;
                u.f = xr[q];
#pragma unroll
                for (int p = 0; p < 4; ++p) {
                    As[c0 + q * 8 + 2 * p + 0][n] = __low2float(u.h[p]);
                    As[c0 + q * 8 + 2 * p + 1][n] = __high2float(u.h[p]);
                }
            }
#pragma unroll
            for (int q = 0; q < 4; ++q) {
                float4 g = gr[q];
                As[64 + c0 + q * 4 + 0][n] = g.x;
                As[64 + c0 + q * 4 + 1][n] = g.y;
                As[64 + c0 + q * 4 + 2][n] = g.z;
                As[64 + c0 + q * 4 + 3][n] = g.w;
            }
        } else {
#pragma unroll
            for (int i = 0; i < 16; ++i) {
                As[c0 + i][n] = 0.f;
                As[64 + c0 + i][n] = 0.f;
            }
        }
    }
    __syncthreads();

    int o0 = (t & 15) * 4;
    int n0 = (t >> 4) * 4;
    float acc[4][4];
#pragma unroll
    for (int i = 0; i < 4; ++i)
#pragma unroll
        for (int jj = 0; jj < 4; ++jj) acc[i][jj] = 0.f;

#pragma unroll 4
    for (int k = 0; k < 128; ++k) {
        float4 a = *(const float4*)&As[k][n0];
        float4 w = *(const float4*)&Ws[k][o0];
        acc[0][0] += a.x * w.x; acc[0][1] += a.x * w.y; acc[0][2] += a.x * w.z; acc[0][3] += a.x * w.w;
        acc[1][0] += a.y * w.x; acc[1][1] += a.y * w.y; acc[1][2] += a.y * w.z; acc[1][3] += a.y * w.w;
        acc[2][0] += a.z * w.x; acc[2][1] += a.z * w.y; acc[2][2] += a.z * w.z; acc[2][3] += a.z * w.w;
        acc[3][0] += a.w * w.x; acc[3][1] += a.w * w.y; acc[3][2] += a.w * w.z; acc[3][3] += a.w * w.w;
    }

    float4 bv = *(const float4*)&bias[o0];
#pragma unroll
    for (int i = 0; i < 4; ++i) {
        int gn = base + n0 + i;
        if (gn < N) {
            float rx = acc[i][0] + bv.x;
            float ry = acc[i][1] + bv.y;
            float rz = acc[i][2] + bv.z;
            float rw = acc[i][3] + bv.w;
            if (do_relu) {
                rx = fmaxf(rx, 0.f); ry = fmaxf(ry, 0.f);
                rz = fmaxf(rz, 0.f); rw = fmaxf(rw, 0.f);
            }
            union { __half2 h[2]; float2 f; } u;
            u.h[0] = __floats2half2_rn(rx, ry);
            u.h[1] = __floats2half2_rn(rz, rw);
            *(float2*)(OUT + (size_t)gn * CH + o0) = u.f;
        }
    }
}

// ---- Layer-3 scalar dots: t[n]=h2[n].W3[0:64], s[n]=h2[n].W3[64:128] ----
__global__ __launch_bounds__(256) void k_dot(const float4* __restrict__ H4,
                                             const float* __restrict__ W3,
                                             float* __restrict__ tarr,
                                             float* __restrict__ sarr, int N) {
    int t = threadIdx.x;
    int sub = t & 7;
    int node = blockIdx.x * 32 + (t >> 3);
    if (node >= N) return;
    float4 r = H4[(size_t)node * 8 + sub];
    const __half2* h = (const __half2*)&r;
    const float4* w = (const float4*)W3;
    float4 ws0 = w[sub * 2],      ws1 = w[sub * 2 + 1];
    float4 wa0 = w[16 + sub * 2], wa1 = w[17 + sub * 2];
    float2 f0 = __half22float2(h[0]), f1 = __half22float2(h[1]);
    float2 f2 = __half22float2(h[2]), f3 = __half22float2(h[3]);
    float tv = f0.x * ws0.x + f0.y * ws0.y + f1.x * ws0.z + f1.y * ws0.w
             + f2.x * ws1.x + f2.y * ws1.y + f3.x * ws1.z + f3.y * ws1.w;
    float sv = f0.x * wa0.x + f0.y * wa0.y + f1.x * wa0.z + f1.y * wa0.w
             + f2.x * wa1.x + f2.y * wa1.y + f3.x * wa1.z + f3.y * wa1.w;
    tv += __shfl_down(tv, 4, 64); tv += __shfl_down(tv, 2, 64); tv += __shfl_down(tv, 1, 64);
    sv += __shfl_down(sv, 4, 64); sv += __shfl_down(sv, 2, 64); sv += __shfl_down(sv, 1, 64);
    if (sub == 0) { tarr[node] = tv; sarr[node] = sv; }
}

// ---- Final: out[n] = t[n] + mean_j s[col_j] + b3 (4B/edge gather) ----
__global__ __launch_bounds__(256) void k_fin(const float* __restrict__ tarr,
                                             const float* __restrict__ sarr,
                                             const int* __restrict__ offs,
                                             const int* __restrict__ scol,
                                             const float* __restrict__ b3,
                                             float* __restrict__ out, int N) {
    int n = blockIdx.x * 256 + threadIdx.x;
    if (n >= N) return;
    int s = offs[n], e = offs[n + 1];
    float s0 = 0.f, s1 = 0.f, s2 = 0.f, s3 = 0.f;
    int j = s;
    for (; j + 4 <= e; j += 4) {
        s0 += sarr[scol[j]];
        s1 += sarr[scol[j + 1]];
        s2 += sarr[scol[j + 2]];
        s3 += sarr[scol[j + 3]];
    }
    for (; j < e; ++j) s0 += sarr[scol[j]];
    float inv = (e > s) ? 1.0f / (float)(e - s) : 1.0f;
    out[n] = tarr[n] + ((s0 + s1) + (s2 + s3)) * inv + b3[0];
}

extern "C" void kernel_launch(void* const* d_in, const int* in_sizes, int n_in,
                              void* d_out, int out_size, void* d_ws, size_t ws_size,
                              hipStream_t stream) {
    const float* x   = (const float*)d_in[0];
    const int* eidx  = (const int*)d_in[1];
    const float* W1  = (const float*)d_in[2];
    const float* b1  = (const float*)d_in[3];
    const float* W2  = (const float*)d_in[4];
    const float* b2  = (const float*)d_in[5];
    const float* W3  = (const float*)d_in[6];
    const float* b3  = (const float*)d_in[7];
    float* out = (float*)d_out;

    const int N = in_sizes[0] / CH;
    const int E = in_sizes[1] / 2;
    const int* row = eidx;
    const int* col = eidx + E;

    int offs_sz = ((N + 1 + 3) / 4) * 4;
    int e_sz    = ((E + 3) / 4) * 4;
    size_t tbl  = (size_t)(N + 1) * CH;  // halves per table (incl. zero row)

    int* offs  = (int*)d_ws;                       // offs_sz
    int* scol  = offs + offs_sz;                   // e_sz
    __half* xh = (__half*)(scol + e_sz);           // tbl halves
    __half* h1 = xh + tbl;
    __half* h2 = h1 + tbl;
    float* agg = (float*)(h2 + tbl);               // N*64 floats
    // sort scratch aliases agg region (dead before agg's first write)
    int* ebuf   = (int*)agg;                       // E
    int nbk     = (N + BKT_ROWS - 1) >> BKT_SHIFT;
    int* hist   = ebuf + e_sz;                     // nbk*NBLK
    int* histsc = hist + (size_t)nbk * NBLK;
    int* part   = histsc + (size_t)nbk * NBLK;     // 64
    // layer-3 scalars also alias agg region (agg dead after layer-2 GEMM)
    float* tarr = agg;                             // N
    float* sarr = agg + N;                         // N

    int M = nbk * NBLK;
    int per_blk = (E + NBLK - 1) / NBLK;
    int mb = (M + 1023) / 1024;
    int abl = (N + 3) / 4;
    int gbl = (N + 63) / 64;
    int cvb = (N * CH / 4 + 255) / 256;

    // CSR build
    k_hist<<<NBLK, 256, 0, stream>>>(row, hist, E, nbk, per_blk);
    k_ssum<<<mb, 256, 0, stream>>>(hist, part, M);
    k_sser<<<1, 64, 0, stream>>>(part, mb);
    k_sscan<<<mb, 256, 0, stream>>>(hist, part, histsc, M);
    k_binscatter<<<NBLK, 256, 0, stream>>>(row, col, histsc, ebuf, E, nbk, per_blk);
    k_build<<<nbk, 256, 0, stream>>>(histsc, ebuf, offs, scol, N, E, nbk);

    // x -> fp16 table; zero dummy rows
    k_tohalf<<<cvb, 256, 0, stream>>>(x, xh, N * CH);
    k_zrow<<<1, 64, 0, stream>>>((float4*)xh, (float4*)h1, (float4*)h2, N);

    // layer 1
    k_agg<<<abl, 256, 0, stream>>>((const float4*)xh, offs, scol, agg, N, E - 1);
    k_gemm<<<gbl, 256, 0, stream>>>(xh, agg, W1, b1, h1, N, 1);
    // layer 2
    k_agg<<<abl, 256, 0, stream>>>((const float4*)h1, offs, scol, agg, N, E - 1);
    k_gemm<<<gbl, 256, 0, stream>>>(h1, agg, W2, b2, h2, N, 1);
    // layer 3: scalar dots + 4B/edge gather
    k_dot<<<(N + 31) / 32, 256, 0, stream>>>((const float4*)h2, W3, tarr, sarr, N);
    k_fin<<<(N + 255) / 256, 256, 0, stream>>>(tarr, sarr, offs, scol, b3, out, N);
}